// Round 1
// baseline (4136.958 us; speedup 1.0000x reference)
//
#include <hip/hip_runtime.h>

typedef unsigned short ushort_t;

#define NWIN 2048
#define NTOK 64
#define QKV_LD 1536
#define ATT_SCALE 0.125f

__device__ inline ushort_t f2bf(float f) {
    unsigned u = __float_as_uint(f);
    u += 0x7fffu + ((u >> 16) & 1u);      // round-to-nearest-even
    return (ushort_t)(u >> 16);
}
__device__ inline float bl(unsigned u) { return __uint_as_float(u << 16); }
__device__ inline float bh(unsigned u) { return __uint_as_float(u & 0xffff0000u); }
__device__ inline void unpack8(uint4 u, float* f) {
    f[0] = bl(u.x); f[1] = bh(u.x); f[2] = bl(u.y); f[3] = bh(u.y);
    f[4] = bl(u.z); f[5] = bh(u.z); f[6] = bl(u.w); f[7] = bh(u.w);
}
__device__ inline float clampn(float n) { return fminf(fmaxf(n, 1e-20f), 1e10f); }

// ---------------------------------------------------------------------------
// Kernel 1: per-window mult map = shadow * dino * plane * cc * mm  [B,64,64]
// ---------------------------------------------------------------------------
__global__ __launch_bounds__(256) void mult_kernel(
    const float* __restrict__ dino, const float* __restrict__ point,
    const float* __restrict__ sdf, const float* __restrict__ normal,
    const float* __restrict__ smask, const float* __restrict__ cmask,
    float* __restrict__ multo)
{
    __shared__ float chs[64][68];     // dino chunk staging
    __shared__ float sdfs[64][20];
    __shared__ float pts[64][4];
    __shared__ float nrs[64][4];
    __shared__ float cls[64][12];
    __shared__ float smc[64];
    __shared__ float dinv[64];
    __shared__ float sinv[64];
    __shared__ float rpart[4][64];

    int b = blockIdx.x;
    int t = threadIdx.x;
    size_t rbase = (size_t)b * 64;

    if (t < 64) {
        int i = t;
        pts[i][0] = point[(rbase + i) * 3 + 0];
        pts[i][1] = point[(rbase + i) * 3 + 1];
        pts[i][2] = point[(rbase + i) * 3 + 2];
        nrs[i][0] = normal[(rbase + i) * 3 + 0];
        nrs[i][1] = normal[(rbase + i) * 3 + 1];
        nrs[i][2] = normal[(rbase + i) * 3 + 2];
        smc[i] = (smask[rbase + i] < 0.1f) ? 1.0f : 2.0f;
    } else if (t < 128) {
        int i = t - 64;
        float4 c0 = *(const float4*)&cmask[(rbase + i) * 8];
        float4 c1 = *(const float4*)&cmask[(rbase + i) * 8 + 4];
        cls[i][0] = c0.x; cls[i][1] = c0.y; cls[i][2] = c0.z; cls[i][3] = c0.w;
        cls[i][4] = c1.x; cls[i][5] = c1.y; cls[i][6] = c1.z; cls[i][7] = c1.w;
    } else if (t < 192) {
        int i = t - 128;
        float ss = 0.f;
        #pragma unroll
        for (int w = 0; w < 4; ++w) {
            float4 s = *(const float4*)&sdf[(rbase + i) * 16 + w * 4];
            *(float4*)&sdfs[i][w * 4] = s;
            ss += s.x * s.x + s.y * s.y + s.z * s.z + s.w * s.w;
        }
        sinv[i] = 1.0f / clampn(sqrtf(ss));
    }
    {   // dino row norms (4 partials per row)
        int i = t & 63, part = t >> 6;
        const float* dr = dino + (rbase + i) * 384 + part * 96;
        float ss = 0.f;
        for (int d = 0; d < 96; d += 4) {
            float4 v = *(const float4*)&dr[d];
            ss += v.x * v.x + v.y * v.y + v.z * v.z + v.w * v.w;
        }
        rpart[part][i] = ss;
    }
    __syncthreads();
    if (t < 64) {
        float s = rpart[0][t] + rpart[1][t] + rpart[2][t] + rpart[3][t];
        dinv[t] = 1.0f / clampn(sqrtf(s));
    }

    int ti = t >> 4, tj = t & 15;
    int i0 = ti * 4;
    int li = t >> 2, d4 = t & 3;

    // dino raw dot products, 4x4 tile per thread, j strided by 16 (bank-friendly)
    float acc[4][4] = {};
    for (int ch = 0; ch < 6; ++ch) {
        __syncthreads();
        const float* dr = dino + (rbase + li) * 384 + ch * 64 + d4 * 16;
        #pragma unroll
        for (int w = 0; w < 4; ++w)
            *(float4*)&chs[li][d4 * 16 + w * 4] = *(const float4*)&dr[w * 4];
        __syncthreads();
        #pragma unroll 4
        for (int d = 0; d < 64; d += 4) {
            float qa[4][4], kb[4][4];
            #pragma unroll
            for (int ii = 0; ii < 4; ++ii) *(float4*)qa[ii] = *(const float4*)&chs[i0 + ii][d];
            #pragma unroll
            for (int jj = 0; jj < 4; ++jj) *(float4*)kb[jj] = *(const float4*)&chs[tj + jj * 16][d];
            #pragma unroll
            for (int ii = 0; ii < 4; ++ii)
                #pragma unroll
                for (int jj = 0; jj < 4; ++jj)
                    #pragma unroll
                    for (int e = 0; e < 4; ++e)
                        acc[ii][jj] = fmaf(qa[ii][e], kb[jj][e], acc[ii][jj]);
        }
    }

    #pragma unroll
    for (int ii = 0; ii < 4; ++ii) {
        int i = i0 + ii;
        float sdI[16];
        #pragma unroll
        for (int w = 0; w < 4; ++w) *(float4*)&sdI[w * 4] = *(const float4*)&sdfs[i][w * 4];
        float pix = pts[i][0], piy = pts[i][1], piz = pts[i][2];
        float nix = nrs[i][0], niy = nrs[i][1], niz = nrs[i][2];
        float clI[8];
        *(float4*)&clI[0] = *(const float4*)&cls[i][0];
        *(float4*)&clI[4] = *(const float4*)&cls[i][4];
        float smci = smc[i], dvi = dinv[i], svi = sinv[i];
        #pragma unroll
        for (int jj = 0; jj < 4; ++jj) {
            int j = tj + jj * 16;
            float sd = 0.f;
            #pragma unroll
            for (int w = 0; w < 4; ++w) {
                float4 sj = *(const float4*)&sdfs[j][w * 4];
                sd += sdI[w * 4 + 0] * sj.x + sdI[w * 4 + 1] * sj.y +
                      sdI[w * 4 + 2] * sj.z + sdI[w * 4 + 3] * sj.w;
            }
            sd *= svi * sinv[j];
            float shadow = 1.0f - fminf(fmaxf(sd, 0.f), 1.f);
            float dd = acc[ii][jj] * dvi * dinv[j];
            float dmap = fminf(fmaxf(dd, 0.f), 1e10f);
            float dx = pix - pts[j][0], dy = piy - pts[j][1], dz = piz - pts[j][2];
            float Pij = fabsf(dx * nix + dy * niy + dz * niz);
            float Pji = fabsf(dx * nrs[j][0] + dy * nrs[j][1] + dz * nrs[j][2]);
            float plane = __expf(-0.5f * (Pij + Pji));
            float4 cj0 = *(const float4*)&cls[j][0];
            float4 cj1 = *(const float4*)&cls[j][4];
            float cc = clI[0] * cj0.x + clI[1] * cj0.y + clI[2] * cj0.z + clI[3] * cj0.w +
                       clI[4] * cj1.x + clI[5] * cj1.y + clI[6] * cj1.z + clI[7] * cj1.w;
            float mm = (smci * smc[j] == 2.0f) ? 1.0f : 0.2f;
            multo[(size_t)b * 4096 + (size_t)i * 64 + j] = shadow * dmap * plane * cc * mm;
        }
    }
}

// ---------------------------------------------------------------------------
// Kernel 2: qkv = x @ [wq;wkv]^T + bias  -> bf16 [M,1536]
// ---------------------------------------------------------------------------
__global__ __launch_bounds__(256) void gemm_qkv_kernel(
    const float* __restrict__ X, const float* __restrict__ wq,
    const float* __restrict__ bq, const float* __restrict__ wkv,
    const float* __restrict__ bkv, ushort_t* __restrict__ qkv)
{
    __shared__ float As[16][132];
    __shared__ float Bs[16][132];
    int bid = blockIdx.x;
    int bx = bid % 12, by = bid / 12;
    int row0 = by * 128, col0 = bx * 128;
    const float* W; const float* bias; int wr0;
    if (bx < 4) { W = wq;  bias = bq;  wr0 = col0; }
    else        { W = wkv; bias = bkv; wr0 = col0 - 512; }
    int t = threadIdx.x;
    int tm = t >> 4, tn = t & 15;
    int lr = t >> 2, lk = (t & 3) * 4;
    float acc[8][8] = {};
    const float* Xp = X + (size_t)(row0 + lr) * 512 + lk;
    const float* Wp = W + (size_t)(wr0 + lr) * 512 + lk;
    for (int k0 = 0; k0 < 512; k0 += 16) {
        float4 a0 = *(const float4*)(Xp + k0);
        float4 a1 = *(const float4*)(Xp + k0 + 64 * 512);
        float4 b0 = *(const float4*)(Wp + k0);
        float4 b1 = *(const float4*)(Wp + k0 + 64 * 512);
        __syncthreads();
        As[lk + 0][lr] = a0.x; As[lk + 1][lr] = a0.y; As[lk + 2][lr] = a0.z; As[lk + 3][lr] = a0.w;
        As[lk + 0][lr + 64] = a1.x; As[lk + 1][lr + 64] = a1.y; As[lk + 2][lr + 64] = a1.z; As[lk + 3][lr + 64] = a1.w;
        Bs[lk + 0][lr] = b0.x; Bs[lk + 1][lr] = b0.y; Bs[lk + 2][lr] = b0.z; Bs[lk + 3][lr] = b0.w;
        Bs[lk + 0][lr + 64] = b1.x; Bs[lk + 1][lr + 64] = b1.y; Bs[lk + 2][lr + 64] = b1.z; Bs[lk + 3][lr + 64] = b1.w;
        __syncthreads();
        #pragma unroll
        for (int kk = 0; kk < 16; ++kk) {
            float a[8], w[8];
            *(float4*)&a[0] = *(const float4*)&As[kk][tm * 8];
            *(float4*)&a[4] = *(const float4*)&As[kk][tm * 8 + 4];
            *(float4*)&w[0] = *(const float4*)&Bs[kk][tn * 8];
            *(float4*)&w[4] = *(const float4*)&Bs[kk][tn * 8 + 4];
            #pragma unroll
            for (int i = 0; i < 8; ++i)
                #pragma unroll
                for (int j = 0; j < 8; ++j)
                    acc[i][j] = fmaf(a[i], w[j], acc[i][j]);
        }
    }
    float bv[8];
    #pragma unroll
    for (int c = 0; c < 8; ++c) bv[c] = bias[wr0 + tn * 8 + c];
    #pragma unroll
    for (int r = 0; r < 8; ++r) {
        int row = row0 + tm * 8 + r;
        union { ushort_t us[8]; uint4 v; } pk;
        #pragma unroll
        for (int c = 0; c < 8; ++c) pk.us[c] = f2bf(acc[r][c] + bv[c]);
        *(uint4*)(qkv + (size_t)row * QKV_LD + col0 + tn * 8) = pk.v;
    }
}

// ---------------------------------------------------------------------------
// Kernel 3: per-window attention; writes ctx (bf16) over the q region of qkv
// ---------------------------------------------------------------------------
__global__ __launch_bounds__(256) void attn_kernel(
    ushort_t* qkv, const float* __restrict__ mult, const float* __restrict__ table)
{
    __shared__ float qs[64][68];
    __shared__ float ks[64][68];
    __shared__ unsigned vsu[64][36];   // v packed as bf16 pairs
    __shared__ float ps[64][68];

    int b = blockIdx.x, t = threadIdx.x;
    size_t base = (size_t)b * 64 * QKV_LD;
    int li = t >> 2, seg = t & 3;
    int ti = t >> 4, tj = t & 15;
    int i0 = ti * 4;
    int i2 = t >> 3, dq = t & 7;
    int ia = i2 * 2, ib = ia + 1, d0 = dq * 8;

    for (int h = 0; h < 8; ++h) {
        __syncthreads();
        {
            const ushort_t* row = qkv + base + (size_t)li * QKV_LD;
            uint4 u0 = *(const uint4*)(row + h * 64 + seg * 16);
            uint4 u1 = *(const uint4*)(row + h * 64 + seg * 16 + 8);
            float f[16]; unpack8(u0, f); unpack8(u1, f + 8);
            #pragma unroll
            for (int w = 0; w < 4; ++w) *(float4*)&qs[li][seg * 16 + w * 4] = *(float4*)&f[w * 4];
            uint4 k0u = *(const uint4*)(row + 512 + h * 64 + seg * 16);
            uint4 k1u = *(const uint4*)(row + 512 + h * 64 + seg * 16 + 8);
            unpack8(k0u, f); unpack8(k1u, f + 8);
            #pragma unroll
            for (int w = 0; w < 4; ++w) *(float4*)&ks[li][seg * 16 + w * 4] = *(float4*)&f[w * 4];
            uint4 v0u = *(const uint4*)(row + 1024 + h * 64 + seg * 16);
            uint4 v1u = *(const uint4*)(row + 1024 + h * 64 + seg * 16 + 8);
            *(uint4*)&vsu[li][seg * 8] = v0u;
            *(uint4*)&vsu[li][seg * 8 + 4] = v1u;
        }
        __syncthreads();

        float acc[4][4] = {};
        #pragma unroll 4
        for (int d = 0; d < 64; d += 4) {
            float qa[4][4], kb[4][4];
            #pragma unroll
            for (int ii = 0; ii < 4; ++ii) *(float4*)qa[ii] = *(const float4*)&qs[i0 + ii][d];
            #pragma unroll
            for (int jj = 0; jj < 4; ++jj) *(float4*)kb[jj] = *(const float4*)&ks[tj + jj * 16][d];
            #pragma unroll
            for (int ii = 0; ii < 4; ++ii)
                #pragma unroll
                for (int jj = 0; jj < 4; ++jj)
                    #pragma unroll
                    for (int e = 0; e < 4; ++e)
                        acc[ii][jj] = fmaf(qa[ii][e], kb[jj][e], acc[ii][jj]);
        }

        #pragma unroll
        for (int ii = 0; ii < 4; ++ii) {
            int i = i0 + ii;
            int ri = i >> 3, ci = i & 7;
            float lg[4];
            #pragma unroll
            for (int jj = 0; jj < 4; ++jj) {
                int j = tj + jj * 16;
                int rj = j >> 3, cj = j & 7;
                int idx = (ri - rj + 7) * 15 + (ci - cj + 7);
                float bias = table[idx * 8 + h];
                float m = mult[(size_t)b * 4096 + (size_t)i * 64 + j];
                lg[jj] = acc[ii][jj] * (ATT_SCALE * m) + bias;
            }
            float mx = fmaxf(fmaxf(lg[0], lg[1]), fmaxf(lg[2], lg[3]));
            #pragma unroll
            for (int s = 1; s <= 8; s <<= 1) mx = fmaxf(mx, __shfl_xor(mx, s));
            float pr[4], sum = 0.f;
            #pragma unroll
            for (int jj = 0; jj < 4; ++jj) { pr[jj] = __expf(lg[jj] - mx); sum += pr[jj]; }
            #pragma unroll
            for (int s = 1; s <= 8; s <<= 1) sum += __shfl_xor(sum, s);
            float inv = 1.0f / sum;
            #pragma unroll
            for (int jj = 0; jj < 4; ++jj) ps[i][tj + jj * 16] = pr[jj] * inv;
        }
        __syncthreads();

        float c0[8] = {}, c1[8] = {};
        #pragma unroll 4
        for (int j = 0; j < 64; ++j) {
            float a0 = ps[ia][j], a1 = ps[ib][j];
            uint4 vv = *(const uint4*)&vsu[j][dq * 4];
            float vf[8]; unpack8(vv, vf);
            #pragma unroll
            for (int e = 0; e < 8; ++e) {
                c0[e] = fmaf(a0, vf[e], c0[e]);
                c1[e] = fmaf(a1, vf[e], c1[e]);
            }
        }
        union { ushort_t us[8]; uint4 v; } p0, p1;
        #pragma unroll
        for (int e = 0; e < 8; ++e) { p0.us[e] = f2bf(c0[e]); p1.us[e] = f2bf(c1[e]); }
        *(uint4*)(qkv + base + (size_t)ia * QKV_LD + h * 64 + d0) = p0.v;
        *(uint4*)(qkv + base + (size_t)ib * QKV_LD + h * 64 + d0) = p1.v;
    }
}

// ---------------------------------------------------------------------------
// Kernel 4: out = ctx(bf16, LD 1536) @ wproj^T + bproj  -> fp32 d_out
// ---------------------------------------------------------------------------
__global__ __launch_bounds__(256) void gemm_proj_kernel(
    const ushort_t* __restrict__ ctx, const float* __restrict__ wproj,
    const float* __restrict__ bproj, float* __restrict__ out)
{
    __shared__ float As[16][132];
    __shared__ float Bs[16][132];
    int bid = blockIdx.x;
    int bx = bid & 3, by = bid >> 2;
    int row0 = by * 128, col0 = bx * 128;
    int t = threadIdx.x;
    int tm = t >> 4, tn = t & 15;
    int lr2 = t >> 1, sg = t & 1;
    int lr = t >> 2, lk = (t & 3) * 4;
    float acc[8][8] = {};
    const ushort_t* Ap = ctx + (size_t)(row0 + lr2) * QKV_LD + sg * 8;
    const float* Wp = wproj + (size_t)(col0 + lr) * 512 + lk;
    for (int k0 = 0; k0 < 512; k0 += 16) {
        uint4 ar = *(const uint4*)(Ap + k0);
        float4 b0 = *(const float4*)(Wp + k0);
        float4 b1 = *(const float4*)(Wp + k0 + 64 * 512);
        float af[8]; unpack8(ar, af);
        __syncthreads();
        #pragma unroll
        for (int w = 0; w < 8; ++w) As[sg * 8 + w][lr2] = af[w];
        Bs[lk + 0][lr] = b0.x; Bs[lk + 1][lr] = b0.y; Bs[lk + 2][lr] = b0.z; Bs[lk + 3][lr] = b0.w;
        Bs[lk + 0][lr + 64] = b1.x; Bs[lk + 1][lr + 64] = b1.y; Bs[lk + 2][lr + 64] = b1.z; Bs[lk + 3][lr + 64] = b1.w;
        __syncthreads();
        #pragma unroll
        for (int kk = 0; kk < 16; ++kk) {
            float a[8], w[8];
            *(float4*)&a[0] = *(const float4*)&As[kk][tm * 8];
            *(float4*)&a[4] = *(const float4*)&As[kk][tm * 8 + 4];
            *(float4*)&w[0] = *(const float4*)&Bs[kk][tn * 8];
            *(float4*)&w[4] = *(const float4*)&Bs[kk][tn * 8 + 4];
            #pragma unroll
            for (int i = 0; i < 8; ++i)
                #pragma unroll
                for (int j = 0; j < 8; ++j)
                    acc[i][j] = fmaf(a[i], w[j], acc[i][j]);
        }
    }
    float bv[8];
    #pragma unroll
    for (int c = 0; c < 8; ++c) bv[c] = bproj[col0 + tn * 8 + c];
    #pragma unroll
    for (int r = 0; r < 8; ++r) {
        int row = row0 + tm * 8 + r;
        float4 o0, o1;
        o0.x = acc[r][0] + bv[0]; o0.y = acc[r][1] + bv[1];
        o0.z = acc[r][2] + bv[2]; o0.w = acc[r][3] + bv[3];
        o1.x = acc[r][4] + bv[4]; o1.y = acc[r][5] + bv[5];
        o1.z = acc[r][6] + bv[6]; o1.w = acc[r][7] + bv[7];
        *(float4*)(out + (size_t)row * 512 + col0 + tn * 8) = o0;
        *(float4*)(out + (size_t)row * 512 + col0 + tn * 8 + 4) = o1;
    }
}

extern "C" void kernel_launch(void* const* d_in, const int* in_sizes, int n_in,
                              void* d_out, int out_size, void* d_ws, size_t ws_size,
                              hipStream_t stream)
{
    const float* x      = (const float*)d_in[0];
    const float* dino   = (const float*)d_in[1];
    const float* point  = (const float*)d_in[2];
    // d_in[3] color_feature unused by reference
    const float* sdf    = (const float*)d_in[4];
    const float* normal = (const float*)d_in[5];
    const float* smask  = (const float*)d_in[6];
    const float* cmask  = (const float*)d_in[7];
    const float* wq     = (const float*)d_in[8];
    const float* bq     = (const float*)d_in[9];
    const float* wkv    = (const float*)d_in[10];
    const float* bkv    = (const float*)d_in[11];
    const float* table  = (const float*)d_in[12];
    const float* wproj  = (const float*)d_in[13];
    const float* bproj  = (const float*)d_in[14];

    ushort_t* qkv = (ushort_t*)d_ws;      // [131072, 1536] bf16 = 402 MB
    float* mult   = (float*)d_out;        // mult map parks in d_out (33.5 MB);
                                          // proj overwrites d_out only after attn consumed it
    float* out    = (float*)d_out;

    hipLaunchKernelGGL(mult_kernel, dim3(NWIN), dim3(256), 0, stream,
                       dino, point, sdf, normal, smask, cmask, mult);
    hipLaunchKernelGGL(gemm_qkv_kernel, dim3(1024 * 12), dim3(256), 0, stream,
                       x, wq, bq, wkv, bkv, qkv);
    hipLaunchKernelGGL(attn_kernel, dim3(NWIN), dim3(256), 0, stream,
                       qkv, mult, table);
    hipLaunchKernelGGL(gemm_proj_kernel, dim3(1024 * 4), dim3(256), 0, stream,
                       qkv, wproj, bproj, out);
}

// Round 2
// 1573.813 us; speedup vs baseline: 2.6286x; 2.6286x over previous
//
#include <hip/hip_runtime.h>

typedef unsigned short ushort_t;
typedef __bf16 bf16x8 __attribute__((ext_vector_type(8)));
typedef float f32x4 __attribute__((ext_vector_type(4)));

#define NWIN 2048
#define QKV_LD 1536
#define ATT_SCALE 0.125f

__device__ inline ushort_t f2bf(float f) {
    unsigned u = __float_as_uint(f);
    u += 0x7fffu + ((u >> 16) & 1u);      // round-to-nearest-even
    return (ushort_t)(u >> 16);
}
__device__ inline float bl(unsigned u) { return __uint_as_float(u << 16); }
__device__ inline float bh(unsigned u) { return __uint_as_float(u & 0xffff0000u); }
__device__ inline void unpack8(uint4 u, float* f) {
    f[0] = bl(u.x); f[1] = bh(u.x); f[2] = bl(u.y); f[3] = bh(u.y);
    f[4] = bl(u.z); f[5] = bh(u.z); f[6] = bl(u.w); f[7] = bh(u.w);
}
__device__ inline float clampn(float n) { return fminf(fmaxf(n, 1e-20f), 1e10f); }

// async 16B global -> LDS (wave-uniform base + lane*16 semantics)
__device__ inline void async_copy16(const void* g, void* l) {
    __builtin_amdgcn_global_load_lds(
        (const __attribute__((address_space(1))) unsigned*)g,
        (__attribute__((address_space(3))) unsigned*)l, 16, 0, 0);
}

// ---------------------------------------------------------------------------
// fp32 -> bf16 converters
// ---------------------------------------------------------------------------
__global__ __launch_bounds__(256) void convert_x_kernel(
    const float* __restrict__ x, ushort_t* __restrict__ xbf)
{
    size_t i = ((size_t)blockIdx.x * 256 + threadIdx.x) * 8;
    float4 a = *(const float4*)&x[i];
    float4 b = *(const float4*)&x[i + 4];
    union { ushort_t us[8]; uint4 v; } p;
    p.us[0] = f2bf(a.x); p.us[1] = f2bf(a.y); p.us[2] = f2bf(a.z); p.us[3] = f2bf(a.w);
    p.us[4] = f2bf(b.x); p.us[5] = f2bf(b.y); p.us[6] = f2bf(b.z); p.us[7] = f2bf(b.w);
    *(uint4*)&xbf[i] = p.v;
}

__global__ __launch_bounds__(256) void convert_w_kernel(
    const float* __restrict__ wq, const float* __restrict__ wkv,
    ushort_t* __restrict__ wqkvbf)
{
    size_t i = ((size_t)blockIdx.x * 256 + threadIdx.x) * 8;   // 786432 total
    const float* src = (i < 262144) ? (wq + i) : (wkv + (i - 262144));
    float4 a = *(const float4*)src;
    float4 b = *(const float4*)(src + 4);
    union { ushort_t us[8]; uint4 v; } p;
    p.us[0] = f2bf(a.x); p.us[1] = f2bf(a.y); p.us[2] = f2bf(a.z); p.us[3] = f2bf(a.w);
    p.us[4] = f2bf(b.x); p.us[5] = f2bf(b.y); p.us[6] = f2bf(b.z); p.us[7] = f2bf(b.w);
    *(uint4*)&wqkvbf[i] = p.v;
}

// ---------------------------------------------------------------------------
// Kernel 1: per-window mult map = shadow * dino * plane * cc * mm  [B,64,64]
// (unchanged from round 1 — correct)
// ---------------------------------------------------------------------------
__global__ __launch_bounds__(256) void mult_kernel(
    const float* __restrict__ dino, const float* __restrict__ point,
    const float* __restrict__ sdf, const float* __restrict__ normal,
    const float* __restrict__ smask, const float* __restrict__ cmask,
    float* __restrict__ multo)
{
    __shared__ float chs[64][68];
    __shared__ float sdfs[64][20];
    __shared__ float pts[64][4];
    __shared__ float nrs[64][4];
    __shared__ float cls[64][12];
    __shared__ float smc[64];
    __shared__ float dinv[64];
    __shared__ float sinv[64];
    __shared__ float rpart[4][64];

    int b = blockIdx.x;
    int t = threadIdx.x;
    size_t rbase = (size_t)b * 64;

    if (t < 64) {
        int i = t;
        pts[i][0] = point[(rbase + i) * 3 + 0];
        pts[i][1] = point[(rbase + i) * 3 + 1];
        pts[i][2] = point[(rbase + i) * 3 + 2];
        nrs[i][0] = normal[(rbase + i) * 3 + 0];
        nrs[i][1] = normal[(rbase + i) * 3 + 1];
        nrs[i][2] = normal[(rbase + i) * 3 + 2];
        smc[i] = (smask[rbase + i] < 0.1f) ? 1.0f : 2.0f;
    } else if (t < 128) {
        int i = t - 64;
        float4 c0 = *(const float4*)&cmask[(rbase + i) * 8];
        float4 c1 = *(const float4*)&cmask[(rbase + i) * 8 + 4];
        cls[i][0] = c0.x; cls[i][1] = c0.y; cls[i][2] = c0.z; cls[i][3] = c0.w;
        cls[i][4] = c1.x; cls[i][5] = c1.y; cls[i][6] = c1.z; cls[i][7] = c1.w;
    } else if (t < 192) {
        int i = t - 128;
        float ss = 0.f;
        #pragma unroll
        for (int w = 0; w < 4; ++w) {
            float4 s = *(const float4*)&sdf[(rbase + i) * 16 + w * 4];
            *(float4*)&sdfs[i][w * 4] = s;
            ss += s.x * s.x + s.y * s.y + s.z * s.z + s.w * s.w;
        }
        sinv[i] = 1.0f / clampn(sqrtf(ss));
    }
    {
        int i = t & 63, part = t >> 6;
        const float* dr = dino + (rbase + i) * 384 + part * 96;
        float ss = 0.f;
        for (int d = 0; d < 96; d += 4) {
            float4 v = *(const float4*)&dr[d];
            ss += v.x * v.x + v.y * v.y + v.z * v.z + v.w * v.w;
        }
        rpart[part][i] = ss;
    }
    __syncthreads();
    if (t < 64) {
        float s = rpart[0][t] + rpart[1][t] + rpart[2][t] + rpart[3][t];
        dinv[t] = 1.0f / clampn(sqrtf(s));
    }

    int ti = t >> 4, tj = t & 15;
    int i0 = ti * 4;
    int li = t >> 2, d4 = t & 3;

    float acc[4][4] = {};
    for (int ch = 0; ch < 6; ++ch) {
        __syncthreads();
        const float* dr = dino + (rbase + li) * 384 + ch * 64 + d4 * 16;
        #pragma unroll
        for (int w = 0; w < 4; ++w)
            *(float4*)&chs[li][d4 * 16 + w * 4] = *(const float4*)&dr[w * 4];
        __syncthreads();
        #pragma unroll 4
        for (int d = 0; d < 64; d += 4) {
            float qa[4][4], kb[4][4];
            #pragma unroll
            for (int ii = 0; ii < 4; ++ii) *(float4*)qa[ii] = *(const float4*)&chs[i0 + ii][d];
            #pragma unroll
            for (int jj = 0; jj < 4; ++jj) *(float4*)kb[jj] = *(const float4*)&chs[tj + jj * 16][d];
            #pragma unroll
            for (int ii = 0; ii < 4; ++ii)
                #pragma unroll
                for (int jj = 0; jj < 4; ++jj)
                    #pragma unroll
                    for (int e = 0; e < 4; ++e)
                        acc[ii][jj] = fmaf(qa[ii][e], kb[jj][e], acc[ii][jj]);
        }
    }

    #pragma unroll
    for (int ii = 0; ii < 4; ++ii) {
        int i = i0 + ii;
        float sdI[16];
        #pragma unroll
        for (int w = 0; w < 4; ++w) *(float4*)&sdI[w * 4] = *(const float4*)&sdfs[i][w * 4];
        float pix = pts[i][0], piy = pts[i][1], piz = pts[i][2];
        float nix = nrs[i][0], niy = nrs[i][1], niz = nrs[i][2];
        float clI[8];
        *(float4*)&clI[0] = *(const float4*)&cls[i][0];
        *(float4*)&clI[4] = *(const float4*)&cls[i][4];
        float smci = smc[i], dvi = dinv[i], svi = sinv[i];
        #pragma unroll
        for (int jj = 0; jj < 4; ++jj) {
            int j = tj + jj * 16;
            float sd = 0.f;
            #pragma unroll
            for (int w = 0; w < 4; ++w) {
                float4 sj = *(const float4*)&sdfs[j][w * 4];
                sd += sdI[w * 4 + 0] * sj.x + sdI[w * 4 + 1] * sj.y +
                      sdI[w * 4 + 2] * sj.z + sdI[w * 4 + 3] * sj.w;
            }
            sd *= svi * sinv[j];
            float shadow = 1.0f - fminf(fmaxf(sd, 0.f), 1.f);
            float dd = acc[ii][jj] * dvi * dinv[j];
            float dmap = fminf(fmaxf(dd, 0.f), 1e10f);
            float dx = pix - pts[j][0], dy = piy - pts[j][1], dz = piz - pts[j][2];
            float Pij = fabsf(dx * nix + dy * niy + dz * niz);
            float Pji = fabsf(dx * nrs[j][0] + dy * nrs[j][1] + dz * nrs[j][2]);
            float plane = __expf(-0.5f * (Pij + Pji));
            float4 cj0 = *(const float4*)&cls[j][0];
            float4 cj1 = *(const float4*)&cls[j][4];
            float cc = clI[0] * cj0.x + clI[1] * cj0.y + clI[2] * cj0.z + clI[3] * cj0.w +
                       clI[4] * cj1.x + clI[5] * cj1.y + clI[6] * cj1.z + clI[7] * cj1.w;
            float mm = (smci * smc[j] == 2.0f) ? 1.0f : 0.2f;
            multo[(size_t)b * 4096 + (size_t)i * 64 + j] = shadow * dmap * plane * cc * mm;
        }
    }
}

// ---------------------------------------------------------------------------
// Kernel 2: qkv = x_bf16 @ wqkv_bf16^T + bias  (MFMA, m97 structure)
// 128x128 tile, BK=32, 16x16x32 bf16 MFMA, global_load_lds staging,
// XOR-swizzled 16B-chunk LDS layout (2-way max bank aliasing = free).
// ---------------------------------------------------------------------------
__global__ __launch_bounds__(256) void gemm_qkv_mfma(
    const ushort_t* __restrict__ xbf, const ushort_t* __restrict__ wqkvbf,
    const float* __restrict__ bq, const float* __restrict__ bkv,
    ushort_t* __restrict__ qkv)
{
    __shared__ uint4 AsU[512];   // 128 rows x 32 k, bf16, chunk = m*4 + (kg ^ ((m>>1)&3))
    __shared__ uint4 BsU[512];

    int bid = blockIdx.x;
    int bx = bid % 12, by = bid / 12;
    int row0 = by * 128, col0 = bx * 128;
    const float* bias; int bcol0;
    if (bx < 4) { bias = bq;  bcol0 = col0; }
    else        { bias = bkv; bcol0 = col0 - 512; }

    int t = threadIdx.x;
    int wave = t >> 6, lane = t & 63;
    int wr = wave >> 1, wc = wave & 1;
    int l15 = lane & 15, kq = lane >> 4;

    f32x4 zero = {0.f, 0.f, 0.f, 0.f};
    f32x4 acc[4][4];
    #pragma unroll
    for (int i = 0; i < 4; ++i)
        #pragma unroll
        for (int j = 0; j < 4; ++j) acc[i][j] = zero;

    for (int k0 = 0; k0 < 512; k0 += 32) {
        #pragma unroll
        for (int q = 0; q < 2; ++q) {
            int c = wave * 128 + q * 64 + lane;
            int m = c >> 2, kg = (c & 3) ^ ((m >> 1) & 3);
            async_copy16(xbf + (size_t)(row0 + m) * 512 + k0 + kg * 8, &AsU[c]);
            async_copy16(wqkvbf + (size_t)(col0 + m) * 512 + k0 + kg * 8, &BsU[c]);
        }
        __syncthreads();
        bf16x8 af[4], bf[4];
        #pragma unroll
        for (int ii = 0; ii < 4; ++ii) {
            int M = wr * 64 + ii * 16 + l15;
            af[ii] = *(bf16x8*)&AsU[M * 4 + (kq ^ ((M >> 1) & 3))];
            int Nn = wc * 64 + ii * 16 + l15;
            bf[ii] = *(bf16x8*)&BsU[Nn * 4 + (kq ^ ((Nn >> 1) & 3))];
        }
        #pragma unroll
        for (int ii = 0; ii < 4; ++ii)
            #pragma unroll
            for (int jj = 0; jj < 4; ++jj)
                acc[ii][jj] = __builtin_amdgcn_mfma_f32_16x16x32_bf16(
                    af[ii], bf[jj], acc[ii][jj], 0, 0, 0);
        __syncthreads();
    }

    int crow = kq * 4, ccol = l15;
    #pragma unroll
    for (int ii = 0; ii < 4; ++ii) {
        #pragma unroll
        for (int jj = 0; jj < 4; ++jj) {
            int row = row0 + wr * 64 + ii * 16 + crow;
            int col = col0 + wc * 64 + jj * 16 + ccol;
            float bval = bias[col - (bcol0 >= 0 ? (col0 - bcol0) : 0) - 0];
            // (bias index = col - 512 when bx>=4; compute directly:)
            bval = (bias == bq) ? bq[col] : bkv[col - 512];
            #pragma unroll
            for (int r = 0; r < 4; ++r)
                qkv[(size_t)(row + r) * QKV_LD + col] = f2bf(acc[ii][jj][r] + bval);
        }
    }
}

// ---------------------------------------------------------------------------
// Kernel 3: per-window attention (unchanged from round 1)
// ---------------------------------------------------------------------------
__global__ __launch_bounds__(256) void attn_kernel(
    ushort_t* qkv, const float* __restrict__ mult, const float* __restrict__ table)
{
    __shared__ float qs[64][68];
    __shared__ float ks[64][68];
    __shared__ unsigned vsu[64][36];
    __shared__ float ps[64][68];

    int b = blockIdx.x, t = threadIdx.x;
    size_t base = (size_t)b * 64 * QKV_LD;
    int li = t >> 2, seg = t & 3;
    int ti = t >> 4, tj = t & 15;
    int i0 = ti * 4;
    int i2 = t >> 3, dq = t & 7;
    int ia = i2 * 2, ib = ia + 1, d0 = dq * 8;

    for (int h = 0; h < 8; ++h) {
        __syncthreads();
        {
            const ushort_t* row = qkv + base + (size_t)li * QKV_LD;
            uint4 u0 = *(const uint4*)(row + h * 64 + seg * 16);
            uint4 u1 = *(const uint4*)(row + h * 64 + seg * 16 + 8);
            float f[16]; unpack8(u0, f); unpack8(u1, f + 8);
            #pragma unroll
            for (int w = 0; w < 4; ++w) *(float4*)&qs[li][seg * 16 + w * 4] = *(float4*)&f[w * 4];
            uint4 k0u = *(const uint4*)(row + 512 + h * 64 + seg * 16);
            uint4 k1u = *(const uint4*)(row + 512 + h * 64 + seg * 16 + 8);
            unpack8(k0u, f); unpack8(k1u, f + 8);
            #pragma unroll
            for (int w = 0; w < 4; ++w) *(float4*)&ks[li][seg * 16 + w * 4] = *(float4*)&f[w * 4];
            uint4 v0u = *(const uint4*)(row + 1024 + h * 64 + seg * 16);
            uint4 v1u = *(const uint4*)(row + 1024 + h * 64 + seg * 16 + 8);
            *(uint4*)&vsu[li][seg * 8] = v0u;
            *(uint4*)&vsu[li][seg * 8 + 4] = v1u;
        }
        __syncthreads();

        float acc[4][4] = {};
        #pragma unroll 4
        for (int d = 0; d < 64; d += 4) {
            float qa[4][4], kb[4][4];
            #pragma unroll
            for (int ii = 0; ii < 4; ++ii) *(float4*)qa[ii] = *(const float4*)&qs[i0 + ii][d];
            #pragma unroll
            for (int jj = 0; jj < 4; ++jj) *(float4*)kb[jj] = *(const float4*)&ks[tj + jj * 16][d];
            #pragma unroll
            for (int ii = 0; ii < 4; ++ii)
                #pragma unroll
                for (int jj = 0; jj < 4; ++jj)
                    #pragma unroll
                    for (int e = 0; e < 4; ++e)
                        acc[ii][jj] = fmaf(qa[ii][e], kb[jj][e], acc[ii][jj]);
        }

        #pragma unroll
        for (int ii = 0; ii < 4; ++ii) {
            int i = i0 + ii;
            int ri = i >> 3, ci = i & 7;
            float lg[4];
            #pragma unroll
            for (int jj = 0; jj < 4; ++jj) {
                int j = tj + jj * 16;
                int rj = j >> 3, cj = j & 7;
                int idx = (ri - rj + 7) * 15 + (ci - cj + 7);
                float bias = table[idx * 8 + h];
                float m = mult[(size_t)b * 4096 + (size_t)i * 64 + j];
                lg[jj] = acc[ii][jj] * (ATT_SCALE * m) + bias;
            }
            float mx = fmaxf(fmaxf(lg[0], lg[1]), fmaxf(lg[2], lg[3]));
            #pragma unroll
            for (int s = 1; s <= 8; s <<= 1) mx = fmaxf(mx, __shfl_xor(mx, s));
            float pr[4], sum = 0.f;
            #pragma unroll
            for (int jj = 0; jj < 4; ++jj) { pr[jj] = __expf(lg[jj] - mx); sum += pr[jj]; }
            #pragma unroll
            for (int s = 1; s <= 8; s <<= 1) sum += __shfl_xor(sum, s);
            float inv = 1.0f / sum;
            #pragma unroll
            for (int jj = 0; jj < 4; ++jj) ps[i][tj + jj * 16] = pr[jj] * inv;
        }
        __syncthreads();

        float c0[8] = {}, c1[8] = {};
        #pragma unroll 4
        for (int j = 0; j < 64; ++j) {
            float a0 = ps[ia][j], a1 = ps[ib][j];
            uint4 vv = *(const uint4*)&vsu[j][dq * 4];
            float vf[8]; unpack8(vv, vf);
            #pragma unroll
            for (int e = 0; e < 8; ++e) {
                c0[e] = fmaf(a0, vf[e], c0[e]);
                c1[e] = fmaf(a1, vf[e], c1[e]);
            }
        }
        union { ushort_t us[8]; uint4 v; } p0, p1;
        #pragma unroll
        for (int e = 0; e < 8; ++e) { p0.us[e] = f2bf(c0[e]); p1.us[e] = f2bf(c1[e]); }
        *(uint4*)(qkv + base + (size_t)ia * QKV_LD + h * 64 + d0) = p0.v;
        *(uint4*)(qkv + base + (size_t)ib * QKV_LD + h * 64 + d0) = p1.v;
    }
}

// ---------------------------------------------------------------------------
// Kernel 4: out = ctx(bf16, LD 1536) @ wproj^T + bproj  (MFMA)
// A staged async; B (fp32 wproj) staged via load+convert+ds_write.
// ---------------------------------------------------------------------------
__global__ __launch_bounds__(256) void gemm_proj_mfma(
    const ushort_t* __restrict__ ctx, const float* __restrict__ wproj,
    const float* __restrict__ bproj, float* __restrict__ out)
{
    __shared__ uint4 AsU[512];
    __shared__ uint4 BsU[512];

    int bid = blockIdx.x;
    int bx = bid & 3, by = bid >> 2;
    int row0 = by * 128, col0 = bx * 128;

    int t = threadIdx.x;
    int wave = t >> 6, lane = t & 63;
    int wr = wave >> 1, wc = wave & 1;
    int l15 = lane & 15, kq = lane >> 4;

    f32x4 zero = {0.f, 0.f, 0.f, 0.f};
    f32x4 acc[4][4];
    #pragma unroll
    for (int i = 0; i < 4; ++i)
        #pragma unroll
        for (int j = 0; j < 4; ++j) acc[i][j] = zero;

    for (int k0 = 0; k0 < 512; k0 += 32) {
        #pragma unroll
        for (int q = 0; q < 2; ++q) {
            int c = wave * 128 + q * 64 + lane;
            int m = c >> 2, kg = (c & 3) ^ ((m >> 1) & 3);
            async_copy16(ctx + (size_t)(row0 + m) * QKV_LD + k0 + kg * 8, &AsU[c]);
        }
        #pragma unroll
        for (int q = 0; q < 2; ++q) {
            int c = t + 256 * q;
            int n = c >> 2, kg = (c & 3) ^ ((n >> 1) & 3);
            const float* src = wproj + (size_t)(col0 + n) * 512 + k0 + kg * 8;
            float4 s0 = *(const float4*)src;
            float4 s1 = *(const float4*)(src + 4);
            union { ushort_t us[8]; uint4 v; } p;
            p.us[0] = f2bf(s0.x); p.us[1] = f2bf(s0.y); p.us[2] = f2bf(s0.z); p.us[3] = f2bf(s0.w);
            p.us[4] = f2bf(s1.x); p.us[5] = f2bf(s1.y); p.us[6] = f2bf(s1.z); p.us[7] = f2bf(s1.w);
            BsU[c] = p.v;
        }
        __syncthreads();
        bf16x8 af[4], bf[4];
        #pragma unroll
        for (int ii = 0; ii < 4; ++ii) {
            int M = wr * 64 + ii * 16 + l15;
            af[ii] = *(bf16x8*)&AsU[M * 4 + (kq ^ ((M >> 1) & 3))];
            int Nn = wc * 64 + ii * 16 + l15;
            bf[ii] = *(bf16x8*)&BsU[Nn * 4 + (kq ^ ((Nn >> 1) & 3))];
        }
        #pragma unroll
        for (int ii = 0; ii < 4; ++ii)
            #pragma unroll
            for (int jj = 0; jj < 4; ++jj)
                acc[ii][jj] = __builtin_amdgcn_mfma_f32_16x16x32_bf16(
                    af[ii], bf[jj], acc[ii][jj], 0, 0, 0);
        __syncthreads();
    }

    int crow = kq * 4, ccol = l15;
    #pragma unroll
    for (int ii = 0; ii < 4; ++ii) {
        #pragma unroll
        for (int jj = 0; jj < 4; ++jj) {
            int row = row0 + wr * 64 + ii * 16 + crow;
            int col = col0 + wc * 64 + jj * 16 + ccol;
            float bval = bproj[col];
            #pragma unroll
            for (int r = 0; r < 4; ++r)
                out[(size_t)(row + r) * 512 + col] = acc[ii][jj][r] + bval;
        }
    }
}

extern "C" void kernel_launch(void* const* d_in, const int* in_sizes, int n_in,
                              void* d_out, int out_size, void* d_ws, size_t ws_size,
                              hipStream_t stream)
{
    const float* x      = (const float*)d_in[0];
    const float* dino   = (const float*)d_in[1];
    const float* point  = (const float*)d_in[2];
    const float* sdf    = (const float*)d_in[4];
    const float* normal = (const float*)d_in[5];
    const float* smask  = (const float*)d_in[6];
    const float* cmask  = (const float*)d_in[7];
    const float* wq     = (const float*)d_in[8];
    const float* bq     = (const float*)d_in[9];
    const float* wkv    = (const float*)d_in[10];
    const float* bkv    = (const float*)d_in[11];
    const float* table  = (const float*)d_in[12];
    const float* wproj  = (const float*)d_in[13];
    const float* bproj  = (const float*)d_in[14];

    // Layout: qkv (402 MB) in ws. Scratch parked in d_out (268 MB), consumed
    // before the final proj GEMM overwrites all of d_out:
    //   [0, 134217728)            x_bf16   (67108864 ushorts)
    //   [134217728, 135790592)    wqkv_bf16 (1536x512)
    //   [136314880, 169869312)    mult map  (2048x4096 fp32)
    char* ob = (char*)d_out;
    ushort_t* xbf    = (ushort_t*)ob;
    ushort_t* wqkvbf = (ushort_t*)(ob + 134217728);
    float*    mult   = (float*)(ob + 136314880);
    ushort_t* qkv    = (ushort_t*)d_ws;
    float*    out    = (float*)d_out;

    hipLaunchKernelGGL(convert_x_kernel, dim3(32768), dim3(256), 0, stream, x, xbf);
    hipLaunchKernelGGL(convert_w_kernel, dim3(384), dim3(256), 0, stream, wq, wkv, wqkvbf);
    hipLaunchKernelGGL(mult_kernel, dim3(NWIN), dim3(256), 0, stream,
                       dino, point, sdf, normal, smask, cmask, mult);
    hipLaunchKernelGGL(gemm_qkv_mfma, dim3(1024 * 12), dim3(256), 0, stream,
                       xbf, wqkvbf, bq, bkv, qkv);
    hipLaunchKernelGGL(attn_kernel, dim3(NWIN), dim3(256), 0, stream,
                       qkv, mult, table);
    hipLaunchKernelGGL(gemm_proj_mfma, dim3(1024 * 4), dim3(256), 0, stream,
                       qkv, wproj, bproj, out);
}